// Round 10
// baseline (28.939 us; speedup 1.0000x reference)
//
#include <hip/hip_runtime.h>
#include <math.h>

#define C_TOTAL 6175
#define BATCH 4096
#define NLEV 4

__device__ __constant__ int PIQ[5] = {0, 25, 175, 1375, 6175};

// argmax merge with first-occurrence (lowest index) tiebreak
__device__ inline void am_merge(float& m, int& idx, float m2, int i2) {
    const bool take = (m2 > m) || (m2 == m && i2 < idx);
    idx = take ? i2 : idx;
    m   = fmaxf(m, m2);
}

// per-element update for component-state j; i is the float4 index in span
__device__ inline void upd(float x, int i, float& m, float& s, int& ii) {
    s += __expf(fminf(x, 60.f));        // baseline-0 exp sum (inputs ~N(0,1))
    ii = (x > m) ? i : ii;              // strict > keeps first occurrence
    m  = fmaxf(m, x);
}

// one wave processes ITS HALF of span p[0..W) (wave w takes float4 chunks
// w*64.., stride 128) and butterfly-reduces within the wave. Peel+tail are
// handled by wave 0's lanes. r7-proven per-span fence structure.
__device__ inline void process_span_half(const float* __restrict__ p, int W,
                                         int t, float& S, float& M, int& I) {
    const int lane = t & 63;

    float ms = -INFINITY, ss = 0.f;
    int   is_ = 0x7fffffff;

    // peel to 16B alignment (p is always 4B aligned); pe <= 3 -> wave 0 only
    int pe = (int)((4u - ((((uintptr_t)p) >> 2) & 3u)) & 3u);
    if (pe > W) pe = W;
    if (t < pe) {
        const float x = p[t];
        ss = __expf(fminf(x, 60.f));
        ms = x; is_ = t;
    }
    const int rem  = W - pe;
    const int nvec = rem >> 2;
    const int tail = rem & 3;
    const float4* vp = reinterpret_cast<const float4*>(p + pe);

    // 4 independent component states (index = float4 index within span)
    float m0 = -INFINITY, m1 = -INFINITY, m2 = -INFINITY, m3 = -INFINITY;
    float s0 = 0.f, s1 = 0.f, s2 = 0.f, s3 = 0.f;
    int   i0 = 0x1fffffff, i1 = 0x1fffffff, i2 = 0x1fffffff, i3 = 0x1fffffff;

    int i = t;                       // t = w*64 + lane: global float4 index
    for (; i + 128 < nvec; i += 256) {   // 2 float4 loads in flight
        const float4 a = vp[i];
        const float4 b = vp[i + 128];
        upd(a.x, i,       m0, s0, i0); upd(a.y, i,       m1, s1, i1);
        upd(a.z, i,       m2, s2, i2); upd(a.w, i,       m3, s3, i3);
        upd(b.x, i + 128, m0, s0, i0); upd(b.y, i + 128, m1, s1, i1);
        upd(b.z, i + 128, m2, s2, i2); upd(b.w, i + 128, m3, s3, i3);
    }
    for (; i < nvec; i += 128) {
        const float4 a = vp[i];
        upd(a.x, i, m0, s0, i0); upd(a.y, i, m1, s1, i1);
        upd(a.z, i, m2, s2, i2); upd(a.w, i, m3, s3, i3);
    }
    if (t < tail) {                  // tail <= 3 -> wave 0 only
        const int c = pe + 4 * nvec + t;
        const float x = p[c];
        ss += __expf(fminf(x, 60.f));
        const bool take = (x > ms) || (x == ms && c < is_);
        is_ = take ? c : is_;
        ms  = fmaxf(ms, x);
    }

    // fold component states (convert float4 index -> element index)
    float m = ms; int idx = is_;
    float s = ss + ((s0 + s1) + (s2 + s3));
    am_merge(m, idx, m0, pe + 4 * i0 + 0);
    am_merge(m, idx, m1, pe + 4 * i1 + 1);
    am_merge(m, idx, m2, pe + 4 * i2 + 2);
    am_merge(m, idx, m3, pe + 4 * i3 + 3);

    // 64-lane butterfly within this wave
    #pragma unroll
    for (int off = 1; off < 64; off <<= 1) {
        const float mm = __shfl_xor(m, off);
        const int   im = __shfl_xor(idx, off);
        const float sm = __shfl_xor(s, off);
        s += sm;
        am_merge(m, idx, mm, im);
    }
    S = s; M = m; I = idx;
}

__global__ __launch_bounds__(128, 8) void taxa_row_kernel(
    const float* __restrict__ y_pred,
    const int*   __restrict__ y_true,
    const float* __restrict__ H,
    const int*   __restrict__ parent,
    float*       __restrict__ ws)   // [BATCH] per-row weighted loss terms
{
    const int t    = threadIdx.x;   // 128 threads = 2 waves share one row
    const int lane = t & 63;
    const int w    = t >> 6;
    const int row  = blockIdx.x;
    const float* rp = y_pred + (long long)row * C_TOTAL;

    // ancestor chain -> local labels per level (uniform scalar loads)
    const int g3 = y_true[row] + 1375;
    const int g2 = parent[g3];
    const int g1 = parent[g2];
    const int g0 = parent[g1];
    int lab[NLEV];
    lab[0] = g0;
    lab[1] = g1 - 25;
    lab[2] = g2 - 175;
    lab[3] = g3 - 1375;

    __shared__ float sM[2][NLEV], sS[2][NLEV];
    __shared__ int   sI[2][NLEV];

    #pragma unroll
    for (int k = 0; k < NLEV; ++k) {
        float S, M;
        int I;
        process_span_half(rp + PIQ[k], PIQ[k + 1] - PIQ[k], t, S, M, I);
        if (lane == 0) { sM[w][k] = M; sS[w][k] = S; sI[w][k] = I; }
    }
    __syncthreads();

    if (t == 0) {
        float ce[NLEV];
        int   am[NLEV];
        #pragma unroll
        for (int k = 0; k < NLEV; ++k) {
            float S = sS[0][k] + sS[1][k];
            float M = sM[0][k];
            int   I = sI[0][k];
            am_merge(M, I, sM[1][k], sI[1][k]);
            ce[k] = __logf(S) - rp[PIQ[k] + lab[k]];  // -log_softmax at label
            am[k] = I;
        }
        float h[3];
        #pragma unroll
        for (int k = 1; k < NLEV; ++k) {
            // faithful quirk: LOCAL argmax indices into global H
            const float hv = H[(long long)am[k - 1] * C_TOTAL + am[k]];
            h[k - 1] = (hv == 0.f) ? 1.f : 0.f;
        }
        // loss = 0.29125*(ce0+pen1+ce1) + 0.165*(pen2+ce2) + 0.1*(pen3+ce3)
        const float invB = 1.0f / 4096.0f;
        const float E    = 2.7182818284590452f;
        ws[row] = 0.29125f * ((ce[0] + ce[1]) * invB + E * h[0])
                + 0.165f  * (ce[2] * invB + E * h[1])
                + 0.10f   * (ce[3] * invB + E * h[2]);
    }
}

__global__ __launch_bounds__(256) void taxa_final_kernel(
    const float* __restrict__ ws, float* __restrict__ out)
{
    const int t = threadIdx.x;
    const float4* v = reinterpret_cast<const float4*>(ws);  // 4096 f32 = 1024 f4
    float a = 0.f;
    #pragma unroll
    for (int j = 0; j < 4; ++j) {
        const float4 x = v[t + 256 * j];
        a += (x.x + x.y) + (x.z + x.w);
    }
    #pragma unroll
    for (int off = 1; off < 64; off <<= 1) a += __shfl_xor(a, off);
    __shared__ float sm[4];
    if ((t & 63) == 0) sm[t >> 6] = a;
    __syncthreads();
    if (t == 0) out[0] = (sm[0] + sm[1]) + (sm[2] + sm[3]);
}

extern "C" void kernel_launch(void* const* d_in, const int* in_sizes, int n_in,
                              void* d_out, int out_size, void* d_ws, size_t ws_size,
                              hipStream_t stream) {
    const float* y_pred = (const float*)d_in[0];
    const int*   y_true = (const int*)d_in[1];
    const float* H      = (const float*)d_in[2];
    const int*   parent = (const int*)d_in[3];
    float* ws  = (float*)d_ws;
    float* out = (float*)d_out;

    taxa_row_kernel<<<dim3(BATCH), dim3(128), 0, stream>>>(y_pred, y_true, H, parent, ws);
    taxa_final_kernel<<<dim3(1), dim3(256), 0, stream>>>(ws, out);
}

// Round 12
// 27.009 us; speedup vs baseline: 1.0715x; 1.0715x over previous
//
#include <hip/hip_runtime.h>
#include <math.h>

#define C_TOTAL 6175
#define BATCH 4096
#define NLEV 4

typedef float f32x4 __attribute__((ext_vector_type(4)));  // native vector: OK for nontemporal builtin

__device__ __constant__ int PIQ[5] = {0, 25, 175, 1375, 6175};

// argmax merge with first-occurrence (lowest index) tiebreak
__device__ inline void am_merge(float& m, int& idx, float m2, int i2) {
    const bool take = (m2 > m) || (m2 == m && i2 < idx);
    idx = take ? i2 : idx;
    m   = fmaxf(m, m2);
}

// per-element update for component-state j; i is the float4 iteration index
__device__ inline void upd(float x, int i, float& m, float& s, int& ii) {
    s += __expf(fminf(x, 60.f));        // baseline-0 exp sum (inputs ~N(0,1))
    ii = (x > m) ? i : ii;              // strict > keeps first occurrence
    m  = fmaxf(m, x);
}

// process span p[0..W) with one 64-lane wave:
// S = sum(exp(x)), (M, I) = max/argmax with first-occurrence tiebreak.
// Butterfly INSIDE per span (r7-proven structure). All streaming loads are
// NON-TEMPORAL: y_pred is read-once, evict-first keeps L2 from thrashing.
__device__ inline void process_span(const float* __restrict__ p, int W,
                                    int lane, float& S, float& M, int& I) {
    // scalar state (real element index) for peel + tail
    float ms = -INFINITY, ss = 0.f;
    int   is_ = 0x7fffffff;

    // peel to 16B alignment (p is always 4B aligned)
    int pe = (int)((4u - ((((uintptr_t)p) >> 2) & 3u)) & 3u);
    if (pe > W) pe = W;
    if (lane < pe) {
        const float x = __builtin_nontemporal_load(p + lane);
        ss = __expf(fminf(x, 60.f));
        ms = x; is_ = lane;
    }
    const int rem  = W - pe;
    const int nvec = rem >> 2;
    const int tail = rem & 3;
    const f32x4* vp = reinterpret_cast<const f32x4*>(p + pe);

    // 4 independent component states (index stored as float4-iteration i)
    float m0 = -INFINITY, m1 = -INFINITY, m2 = -INFINITY, m3 = -INFINITY;
    float s0 = 0.f, s1 = 0.f, s2 = 0.f, s3 = 0.f;
    int   i0 = 0x1fffffff, i1 = 0x1fffffff, i2 = 0x1fffffff, i3 = 0x1fffffff;

    int i = lane;
    // 4 float4 loads in flight (MLP); VGPRs guarded by __launch_bounds__(256,4)
    for (; i + 192 < nvec; i += 256) {
        const f32x4 a = __builtin_nontemporal_load(vp + i);
        const f32x4 b = __builtin_nontemporal_load(vp + i + 64);
        const f32x4 c = __builtin_nontemporal_load(vp + i + 128);
        const f32x4 d = __builtin_nontemporal_load(vp + i + 192);
        upd(a.x, i,       m0, s0, i0); upd(a.y, i,       m1, s1, i1);
        upd(a.z, i,       m2, s2, i2); upd(a.w, i,       m3, s3, i3);
        upd(b.x, i + 64,  m0, s0, i0); upd(b.y, i + 64,  m1, s1, i1);
        upd(b.z, i + 64,  m2, s2, i2); upd(b.w, i + 64,  m3, s3, i3);
        upd(c.x, i + 128, m0, s0, i0); upd(c.y, i + 128, m1, s1, i1);
        upd(c.z, i + 128, m2, s2, i2); upd(c.w, i + 128, m3, s3, i3);
        upd(d.x, i + 192, m0, s0, i0); upd(d.y, i + 192, m1, s1, i1);
        upd(d.z, i + 192, m2, s2, i2); upd(d.w, i + 192, m3, s3, i3);
    }
    for (; i + 64 < nvec; i += 128) {
        const f32x4 a = __builtin_nontemporal_load(vp + i);
        const f32x4 b = __builtin_nontemporal_load(vp + i + 64);
        upd(a.x, i, m0, s0, i0); upd(a.y, i, m1, s1, i1);
        upd(a.z, i, m2, s2, i2); upd(a.w, i, m3, s3, i3);
        upd(b.x, i + 64, m0, s0, i0); upd(b.y, i + 64, m1, s1, i1);
        upd(b.z, i + 64, m2, s2, i2); upd(b.w, i + 64, m3, s3, i3);
    }
    if (i < nvec) {
        const f32x4 a = __builtin_nontemporal_load(vp + i);
        upd(a.x, i, m0, s0, i0); upd(a.y, i, m1, s1, i1);
        upd(a.z, i, m2, s2, i2); upd(a.w, i, m3, s3, i3);
    }
    if (lane < tail) {
        const int c = pe + 4 * nvec + lane;
        const float x = __builtin_nontemporal_load(p + c);
        ss += __expf(fminf(x, 60.f));
        const bool take = (x > ms) || (x == ms && c < is_);
        is_ = take ? c : is_;
        ms  = fmaxf(ms, x);
    }

    // merge component states into scalar state (convert i -> global index)
    float m = ms; int idx = is_;
    float s = ss + ((s0 + s1) + (s2 + s3));
    am_merge(m, idx, m0, pe + 4 * i0 + 0);
    am_merge(m, idx, m1, pe + 4 * i1 + 1);
    am_merge(m, idx, m2, pe + 4 * i2 + 2);
    am_merge(m, idx, m3, pe + 4 * i3 + 3);

    // 64-lane butterfly reduce (all lanes end with the full result)
    #pragma unroll
    for (int off = 1; off < 64; off <<= 1) {
        const float mm = __shfl_xor(m, off);
        const int   im = __shfl_xor(idx, off);
        const float sm = __shfl_xor(s, off);
        s += sm;
        am_merge(m, idx, mm, im);
    }
    S = s; M = m; I = idx;
}

__global__ __launch_bounds__(256, 4) void taxa_row_kernel(
    const float* __restrict__ y_pred,
    const int*   __restrict__ y_true,
    const float* __restrict__ H,
    const int*   __restrict__ parent,
    float*       __restrict__ ws)   // [BATCH] per-row weighted loss terms
{
    const int lane = threadIdx.x & 63;
    const int row  = blockIdx.x * 4 + (threadIdx.x >> 6);
    const float* rp = y_pred + (long long)row * C_TOTAL;

    // ancestor chain -> local labels per level
    const int g3 = y_true[row] + 1375;
    const int g2 = parent[g3];
    const int g1 = parent[g2];
    const int g0 = parent[g1];
    int lab[NLEV];
    lab[0] = g0;
    lab[1] = g1 - 25;
    lab[2] = g2 - 175;
    lab[3] = g3 - 1375;

    float ce[NLEV];
    int   argm[NLEV];

    #pragma unroll
    for (int k = 0; k < NLEV; ++k) {
        const int base = PIQ[k];
        const int W    = PIQ[k + 1] - base;
        float S, M;
        int I;
        process_span(rp + base, W, lane, S, M, I);
        const float xl = rp[base + lab[k]];   // label logit: cached broadcast load
        ce[k]   = __logf(S) - xl;             // -log_softmax at label (baseline 0)
        argm[k] = I;
    }

    if (lane == 0) {
        float h[3];
        #pragma unroll
        for (int k = 1; k < NLEV; ++k) {
            // faithful quirk: LOCAL argmax indices into global H
            const float hv = H[(long long)argm[k - 1] * C_TOTAL + argm[k]];
            h[k - 1] = (hv == 0.f) ? 1.f : 0.f;
        }
        // loss = 0.29125*(ce0+pen1+ce1) + 0.165*(pen2+ce2) + 0.1*(pen3+ce3)
        const float invB = 1.0f / 4096.0f;
        const float E    = 2.7182818284590452f;
        ws[row] = 0.29125f * ((ce[0] + ce[1]) * invB + E * h[0])
                + 0.165f  * (ce[2] * invB + E * h[1])
                + 0.10f   * (ce[3] * invB + E * h[2]);
    }
}

__global__ __launch_bounds__(256) void taxa_final_kernel(
    const float* __restrict__ ws, float* __restrict__ out)
{
    const int t = threadIdx.x;
    const float4* v = reinterpret_cast<const float4*>(ws);  // 4096 f32 = 1024 f4
    float a = 0.f;
    #pragma unroll
    for (int j = 0; j < 4; ++j) {
        const float4 x = v[t + 256 * j];
        a += (x.x + x.y) + (x.z + x.w);
    }
    #pragma unroll
    for (int off = 1; off < 64; off <<= 1) a += __shfl_xor(a, off);
    __shared__ float sm[4];
    if ((t & 63) == 0) sm[t >> 6] = a;
    __syncthreads();
    if (t == 0) out[0] = (sm[0] + sm[1]) + (sm[2] + sm[3]);
}

extern "C" void kernel_launch(void* const* d_in, const int* in_sizes, int n_in,
                              void* d_out, int out_size, void* d_ws, size_t ws_size,
                              hipStream_t stream) {
    const float* y_pred = (const float*)d_in[0];
    const int*   y_true = (const int*)d_in[1];
    const float* H      = (const float*)d_in[2];
    const int*   parent = (const int*)d_in[3];
    float* ws  = (float*)d_ws;
    float* out = (float*)d_out;

    taxa_row_kernel<<<dim3(BATCH / 4), dim3(256), 0, stream>>>(y_pred, y_true, H, parent, ws);
    taxa_final_kernel<<<dim3(1), dim3(256), 0, stream>>>(ws, out);
}

// Round 13
// 25.994 us; speedup vs baseline: 1.1133x; 1.0390x over previous
//
#include <hip/hip_runtime.h>
#include <math.h>

#define C_TOTAL 6175
#define BATCH 4096
#define NLEV 4

__device__ __constant__ int PIQ[5] = {0, 25, 175, 1375, 6175};

// argmax merge with first-occurrence (lowest index) tiebreak
__device__ inline void am_merge(float& m, int& idx, float m2, int i2) {
    const bool take = (m2 > m) || (m2 == m && i2 < idx);
    idx = take ? i2 : idx;
    m   = fmaxf(m, m2);
}

// per-element update for component-state j; i is the float4 iteration index
__device__ inline void upd(float x, int i, float& m, float& s, int& ii) {
    s += __expf(fminf(x, 60.f));        // baseline-0 exp sum (inputs ~N(0,1))
    ii = (x > m) ? i : ii;              // strict > keeps first occurrence
    m  = fmaxf(m, x);
}

// process span p[0..W) with one 64-lane wave:
// S = sum(exp(x)), (M, I) = max/argmax with first-occurrence tiebreak.
// Butterfly INSIDE per span (r7-proven structure).
__device__ inline void process_span(const float* __restrict__ p, int W,
                                    int lane, float& S, float& M, int& I) {
    // scalar state (real element index) for peel + tail
    float ms = -INFINITY, ss = 0.f;
    int   is_ = 0x7fffffff;

    // peel to 16B alignment (p is always 4B aligned)
    int pe = (int)((4u - ((((uintptr_t)p) >> 2) & 3u)) & 3u);
    if (pe > W) pe = W;
    if (lane < pe) {
        const float x = p[lane];
        ss = __expf(fminf(x, 60.f));
        ms = x; is_ = lane;
    }
    const int rem  = W - pe;
    const int nvec = rem >> 2;
    const int tail = rem & 3;
    const float4* vp = reinterpret_cast<const float4*>(p + pe);

    // 4 independent component states (index stored as float4-iteration i)
    float m0 = -INFINITY, m1 = -INFINITY, m2 = -INFINITY, m3 = -INFINITY;
    float s0 = 0.f, s1 = 0.f, s2 = 0.f, s3 = 0.f;
    int   i0 = 0x1fffffff, i1 = 0x1fffffff, i2 = 0x1fffffff, i3 = 0x1fffffff;

    int i = lane;
    // 4 float4 loads in flight (MLP); VGPRs guarded by __launch_bounds__(256,4)
    for (; i + 192 < nvec; i += 256) {
        const float4 a = vp[i];
        const float4 b = vp[i + 64];
        const float4 c = vp[i + 128];
        const float4 d = vp[i + 192];
        upd(a.x, i,       m0, s0, i0); upd(a.y, i,       m1, s1, i1);
        upd(a.z, i,       m2, s2, i2); upd(a.w, i,       m3, s3, i3);
        upd(b.x, i + 64,  m0, s0, i0); upd(b.y, i + 64,  m1, s1, i1);
        upd(b.z, i + 64,  m2, s2, i2); upd(b.w, i + 64,  m3, s3, i3);
        upd(c.x, i + 128, m0, s0, i0); upd(c.y, i + 128, m1, s1, i1);
        upd(c.z, i + 128, m2, s2, i2); upd(c.w, i + 128, m3, s3, i3);
        upd(d.x, i + 192, m0, s0, i0); upd(d.y, i + 192, m1, s1, i1);
        upd(d.z, i + 192, m2, s2, i2); upd(d.w, i + 192, m3, s3, i3);
    }
    for (; i + 64 < nvec; i += 128) {
        const float4 a = vp[i];
        const float4 b = vp[i + 64];
        upd(a.x, i, m0, s0, i0); upd(a.y, i, m1, s1, i1);
        upd(a.z, i, m2, s2, i2); upd(a.w, i, m3, s3, i3);
        upd(b.x, i + 64, m0, s0, i0); upd(b.y, i + 64, m1, s1, i1);
        upd(b.z, i + 64, m2, s2, i2); upd(b.w, i + 64, m3, s3, i3);
    }
    if (i < nvec) {
        const float4 a = vp[i];
        upd(a.x, i, m0, s0, i0); upd(a.y, i, m1, s1, i1);
        upd(a.z, i, m2, s2, i2); upd(a.w, i, m3, s3, i3);
    }
    if (lane < tail) {
        const int c = pe + 4 * nvec + lane;
        const float x = p[c];
        ss += __expf(fminf(x, 60.f));
        const bool take = (x > ms) || (x == ms && c < is_);
        is_ = take ? c : is_;
        ms  = fmaxf(ms, x);
    }

    // merge component states into scalar state (convert i -> global index)
    float m = ms; int idx = is_;
    float s = ss + ((s0 + s1) + (s2 + s3));
    am_merge(m, idx, m0, pe + 4 * i0 + 0);
    am_merge(m, idx, m1, pe + 4 * i1 + 1);
    am_merge(m, idx, m2, pe + 4 * i2 + 2);
    am_merge(m, idx, m3, pe + 4 * i3 + 3);

    // 64-lane butterfly reduce (all lanes end with the full result)
    #pragma unroll
    for (int off = 1; off < 64; off <<= 1) {
        const float mm = __shfl_xor(m, off);
        const int   im = __shfl_xor(idx, off);
        const float sm = __shfl_xor(s, off);
        s += sm;
        am_merge(m, idx, mm, im);
    }
    S = s; M = m; I = idx;
}

// one span, compile-time k: results into statically-indexed slots
#define DO_SPAN(k)                                                          \
    {                                                                       \
        float S, M;                                                         \
        int I;                                                              \
        process_span(rp + PIQ[k], PIQ[(k) + 1] - PIQ[k], lane, S, M, I);    \
        ce[k]   = __logf(S) - rp[PIQ[k] + lab[k]];                          \
        argm[k] = I;                                                        \
    }

__global__ __launch_bounds__(256, 4) void taxa_row_kernel(
    const float* __restrict__ y_pred,
    const int*   __restrict__ y_true,
    const float* __restrict__ H,
    const int*   __restrict__ parent,
    float*       __restrict__ ws)   // [BATCH] per-row weighted loss terms
{
    const int lane = threadIdx.x & 63;
    const int wid  = threadIdx.x >> 6;
    const int row  = blockIdx.x * 4 + wid;
    const float* rp = y_pred + (long long)row * C_TOTAL;

    // ancestor chain -> local labels per level
    const int g3 = y_true[row] + 1375;
    const int g2 = parent[g3];
    const int g1 = parent[g2];
    const int g0 = parent[g1];
    int lab[NLEV];
    lab[0] = g0;
    lab[1] = g1 - 25;
    lab[2] = g2 - 175;
    lab[3] = g3 - 1375;

    float ce[NLEV];
    int   argm[NLEV];

    // Phase decorrelation: rotate span order per wave so SIMD-mates stream
    // big spans while this wave butterflies a small one (spans independent;
    // order is semantics-free). Wave-uniform switch: no divergence, and all
    // ce[]/argm[] indices stay compile-time (no scratch).
    const int start = (blockIdx.x + wid) & 3;
    switch (start) {
        case 0: DO_SPAN(0) DO_SPAN(1) DO_SPAN(2) DO_SPAN(3) break;
        case 1: DO_SPAN(1) DO_SPAN(2) DO_SPAN(3) DO_SPAN(0) break;
        case 2: DO_SPAN(2) DO_SPAN(3) DO_SPAN(0) DO_SPAN(1) break;
        default: DO_SPAN(3) DO_SPAN(0) DO_SPAN(1) DO_SPAN(2) break;
    }

    if (lane == 0) {
        float h[3];
        #pragma unroll
        for (int k = 1; k < NLEV; ++k) {
            // faithful quirk: LOCAL argmax indices into global H
            const float hv = H[(long long)argm[k - 1] * C_TOTAL + argm[k]];
            h[k - 1] = (hv == 0.f) ? 1.f : 0.f;
        }
        // loss = 0.29125*(ce0+pen1+ce1) + 0.165*(pen2+ce2) + 0.1*(pen3+ce3)
        const float invB = 1.0f / 4096.0f;
        const float E    = 2.7182818284590452f;
        ws[row] = 0.29125f * ((ce[0] + ce[1]) * invB + E * h[0])
                + 0.165f  * (ce[2] * invB + E * h[1])
                + 0.10f   * (ce[3] * invB + E * h[2]);
    }
}

__global__ __launch_bounds__(256) void taxa_final_kernel(
    const float* __restrict__ ws, float* __restrict__ out)
{
    const int t = threadIdx.x;
    const float4* v = reinterpret_cast<const float4*>(ws);  // 4096 f32 = 1024 f4
    float a = 0.f;
    #pragma unroll
    for (int j = 0; j < 4; ++j) {
        const float4 x = v[t + 256 * j];
        a += (x.x + x.y) + (x.z + x.w);
    }
    #pragma unroll
    for (int off = 1; off < 64; off <<= 1) a += __shfl_xor(a, off);
    __shared__ float sm[4];
    if ((t & 63) == 0) sm[t >> 6] = a;
    __syncthreads();
    if (t == 0) out[0] = (sm[0] + sm[1]) + (sm[2] + sm[3]);
}

extern "C" void kernel_launch(void* const* d_in, const int* in_sizes, int n_in,
                              void* d_out, int out_size, void* d_ws, size_t ws_size,
                              hipStream_t stream) {
    const float* y_pred = (const float*)d_in[0];
    const int*   y_true = (const int*)d_in[1];
    const float* H      = (const float*)d_in[2];
    const int*   parent = (const int*)d_in[3];
    float* ws  = (float*)d_ws;
    float* out = (float*)d_out;

    taxa_row_kernel<<<dim3(BATCH / 4), dim3(256), 0, stream>>>(y_pred, y_true, H, parent, ws);
    taxa_final_kernel<<<dim3(1), dim3(256), 0, stream>>>(ws, out);
}

// Round 14
// 25.250 us; speedup vs baseline: 1.1461x; 1.0295x over previous
//
#include <hip/hip_runtime.h>
#include <math.h>

#define C_TOTAL 6175
#define BATCH 4096
#define NLEV 4

// argmax merge with first-occurrence (lowest index) tiebreak
__device__ inline void am_merge(float& m, int& idx, float m2, int i2) {
    const bool take = (m2 > m) || (m2 == m && i2 < idx);
    idx = take ? i2 : idx;
    m   = fmaxf(m, m2);
}

// per-element update for component-state j; i is the float4 iteration index
__device__ inline void upd(float x, int i, float& m, float& s, int& ii) {
    s += __expf(x);            // baseline-0 exp sum (inputs ~N(0,1); ref doesn't clamp)
    ii = (x > m) ? i : ii;     // strict > keeps first occurrence
    m  = fmaxf(m, x);
}

// butterfly reduce of (sum s, max m, argmax idx) across the 64-lane wave
__device__ inline void butterfly(float& s, float& m, int& idx) {
    #pragma unroll
    for (int off = 1; off < 64; off <<= 1) {
        const float mm = __shfl_xor(m, off);
        const int   im = __shfl_xor(idx, off);
        const float sm = __shfl_xor(s, off);
        s += sm;
        am_merge(m, idx, mm, im);
    }
}

// process span p[0..W) with one 64-lane wave; W is COMPILE-TIME so dead loop
// tiers fold away per span. Butterfly INSIDE per span (r7-proven structure).
template <int W>
__device__ inline void process_span(const float* __restrict__ p,
                                    int lane, float& S, float& M, int& I) {
    if constexpr (W <= 64) {
        // fast path: one masked scalar load (coalesced), no peel/vec machinery
        const float x = p[lane];                    // lanes 0..63 in-bounds (row len 6175)
        const bool  a = (lane < W);
        float s = a ? __expf(x) : 0.f;
        float m = a ? x : -INFINITY;
        int idx = a ? lane : 0x7fffffff;
        butterfly(s, m, idx);
        S = s; M = m; I = idx;
        return;
    }

    // scalar state (real element index) for peel + tail
    float ms = -INFINITY, ss = 0.f;
    int   is_ = 0x7fffffff;

    // peel to 16B alignment (p is 4B aligned; row stride 6175 is odd -> runtime)
    int pe = (int)((4u - ((((uintptr_t)p) >> 2) & 3u)) & 3u);
    if (lane < pe) {
        const float x = p[lane];
        ss = __expf(x); ms = x; is_ = lane;
    }
    const int rem  = W - pe;
    const int nvec = rem >> 2;
    const int tail = rem & 3;
    const float4* vp = reinterpret_cast<const float4*>(p + pe);

    // 4 independent component states (index stored as float4-iteration i)
    float m0 = -INFINITY, m1 = -INFINITY, m2 = -INFINITY, m3 = -INFINITY;
    float s0 = 0.f, s1 = 0.f, s2 = 0.f, s3 = 0.f;
    int   i0 = 0x1fffffff, i1 = 0x1fffffff, i2 = 0x1fffffff, i3 = 0x1fffffff;

    int i = lane;
    if constexpr (W >= 1024) {
        // 4 float4 loads in flight (MLP); guarded by __launch_bounds__(256,4)
        for (; i + 192 < nvec; i += 256) {
            const float4 a = vp[i];
            const float4 b = vp[i + 64];
            const float4 c = vp[i + 128];
            const float4 d = vp[i + 192];
            upd(a.x, i,       m0, s0, i0); upd(a.y, i,       m1, s1, i1);
            upd(a.z, i,       m2, s2, i2); upd(a.w, i,       m3, s3, i3);
            upd(b.x, i + 64,  m0, s0, i0); upd(b.y, i + 64,  m1, s1, i1);
            upd(b.z, i + 64,  m2, s2, i2); upd(b.w, i + 64,  m3, s3, i3);
            upd(c.x, i + 128, m0, s0, i0); upd(c.y, i + 128, m1, s1, i1);
            upd(c.z, i + 128, m2, s2, i2); upd(c.w, i + 128, m3, s3, i3);
            upd(d.x, i + 192, m0, s0, i0); upd(d.y, i + 192, m1, s1, i1);
            upd(d.z, i + 192, m2, s2, i2); upd(d.w, i + 192, m3, s3, i3);
        }
        for (; i + 64 < nvec; i += 128) {
            const float4 a = vp[i];
            const float4 b = vp[i + 64];
            upd(a.x, i, m0, s0, i0); upd(a.y, i, m1, s1, i1);
            upd(a.z, i, m2, s2, i2); upd(a.w, i, m3, s3, i3);
            upd(b.x, i + 64, m0, s0, i0); upd(b.y, i + 64, m1, s1, i1);
            upd(b.z, i + 64, m2, s2, i2); upd(b.w, i + 64, m3, s3, i3);
        }
    }
    for (; i < nvec; i += 64) {
        const float4 a = vp[i];
        upd(a.x, i, m0, s0, i0); upd(a.y, i, m1, s1, i1);
        upd(a.z, i, m2, s2, i2); upd(a.w, i, m3, s3, i3);
    }
    if (lane < tail) {
        const int c = pe + 4 * nvec + lane;
        const float x = p[c];
        ss += __expf(x);
        const bool take = (x > ms) || (x == ms && c < is_);
        is_ = take ? c : is_;
        ms  = fmaxf(ms, x);
    }

    // merge component states into scalar state (convert i -> global index)
    float m = ms; int idx = is_;
    float s = ss + ((s0 + s1) + (s2 + s3));
    am_merge(m, idx, m0, pe + 4 * i0 + 0);
    am_merge(m, idx, m1, pe + 4 * i1 + 1);
    am_merge(m, idx, m2, pe + 4 * i2 + 2);
    am_merge(m, idx, m3, pe + 4 * i3 + 3);

    butterfly(s, m, idx);
    S = s; M = m; I = idx;
}

// one span, compile-time k: results into statically-indexed slots
#define DO_SPAN(k, Wk)                                                      \
    {                                                                       \
        float S, M;                                                         \
        int I;                                                              \
        process_span<Wk>(rp + piq[k], lane, S, M, I);                       \
        ce[k]   = __logf(S) - rp[piq[k] + lab[k]];                          \
        argm[k] = I;                                                        \
    }

__global__ __launch_bounds__(256, 4) void taxa_row_kernel(
    const float* __restrict__ y_pred,
    const int*   __restrict__ y_true,
    const float* __restrict__ H,
    const int*   __restrict__ parent,
    float*       __restrict__ ws)   // [BATCH] per-row weighted loss terms
{
    constexpr int piq[5] = {0, 25, 175, 1375, 6175};
    const int lane = threadIdx.x & 63;
    const int wid  = threadIdx.x >> 6;
    const int row  = blockIdx.x * 4 + wid;
    const float* rp = y_pred + (long long)row * C_TOTAL;

    // ancestor chain -> local labels per level
    const int g3 = y_true[row] + 1375;
    const int g2 = parent[g3];
    const int g1 = parent[g2];
    const int g0 = parent[g1];
    int lab[NLEV];
    lab[0] = g0;
    lab[1] = g1 - 25;
    lab[2] = g2 - 175;
    lab[3] = g3 - 1375;

    float ce[NLEV];
    int   argm[NLEV];

    // Phase decorrelation (r13, +0.9us): rotate span order per wave so
    // SIMD-mates stream big spans while this wave reduces a small one.
    // Wave-uniform switch; all ce[]/argm[] indices compile-time.
    const int start = (blockIdx.x + wid) & 3;
    switch (start) {
        case 0: DO_SPAN(0, 25) DO_SPAN(1, 150) DO_SPAN(2, 1200) DO_SPAN(3, 4800) break;
        case 1: DO_SPAN(1, 150) DO_SPAN(2, 1200) DO_SPAN(3, 4800) DO_SPAN(0, 25) break;
        case 2: DO_SPAN(2, 1200) DO_SPAN(3, 4800) DO_SPAN(0, 25) DO_SPAN(1, 150) break;
        default: DO_SPAN(3, 4800) DO_SPAN(0, 25) DO_SPAN(1, 150) DO_SPAN(2, 1200) break;
    }

    if (lane == 0) {
        float h[3];
        #pragma unroll
        for (int k = 1; k < NLEV; ++k) {
            // faithful quirk: LOCAL argmax indices into global H
            const float hv = H[(long long)argm[k - 1] * C_TOTAL + argm[k]];
            h[k - 1] = (hv == 0.f) ? 1.f : 0.f;
        }
        // loss = 0.29125*(ce0+pen1+ce1) + 0.165*(pen2+ce2) + 0.1*(pen3+ce3)
        const float invB = 1.0f / 4096.0f;
        const float E    = 2.7182818284590452f;
        ws[row] = 0.29125f * ((ce[0] + ce[1]) * invB + E * h[0])
                + 0.165f  * (ce[2] * invB + E * h[1])
                + 0.10f   * (ce[3] * invB + E * h[2]);
    }
}

__global__ __launch_bounds__(256) void taxa_final_kernel(
    const float* __restrict__ ws, float* __restrict__ out)
{
    const int t = threadIdx.x;
    const float4* v = reinterpret_cast<const float4*>(ws);  // 4096 f32 = 1024 f4
    float a = 0.f;
    #pragma unroll
    for (int j = 0; j < 4; ++j) {
        const float4 x = v[t + 256 * j];
        a += (x.x + x.y) + (x.z + x.w);
    }
    #pragma unroll
    for (int off = 1; off < 64; off <<= 1) a += __shfl_xor(a, off);
    __shared__ float sm[4];
    if ((t & 63) == 0) sm[t >> 6] = a;
    __syncthreads();
    if (t == 0) out[0] = (sm[0] + sm[1]) + (sm[2] + sm[3]);
}

extern "C" void kernel_launch(void* const* d_in, const int* in_sizes, int n_in,
                              void* d_out, int out_size, void* d_ws, size_t ws_size,
                              hipStream_t stream) {
    const float* y_pred = (const float*)d_in[0];
    const int*   y_true = (const int*)d_in[1];
    const float* H      = (const float*)d_in[2];
    const int*   parent = (const int*)d_in[3];
    float* ws  = (float*)d_ws;
    float* out = (float*)d_out;

    taxa_row_kernel<<<dim3(BATCH / 4), dim3(256), 0, stream>>>(y_pred, y_true, H, parent, ws);
    taxa_final_kernel<<<dim3(1), dim3(256), 0, stream>>>(ws, out);
}